// Round 9
// baseline (501.312 us; speedup 1.0000x reference)
//
#include <hip/hip_runtime.h>
#include <hip/hip_cooperative_groups.h>
#include <hip/hip_bf16.h>

namespace cg = cooperative_groups;

#define N_NODES 50000
#define N_EDGES 640000
#define N_REL   200
#define D       128
#define CAP     64              // bucket capacity; max degree ~35 (Poisson 12.8)
#define RANGES  8               // one target-range per XCD
#define NODES_PER_RANGE (N_NODES / RANGES)   // 6250
#define CHUNK_EDGES 2560
#define N_CHUNKS (N_EDGES / CHUNK_EDGES)     // 250

#define A0_UNITS 310            // 64 Wbf + 50 s_rel + 196 count-zero
#define A1_UNITS 1563           // 4 waves each -> 6252 >= 6250 split waves
#define XT_WAVES2 6250
#define SC_UNITS (N_CHUNKS * RANGES)         // 2000
#define G_UNITS  (391 * RANGES)              // 3128 (391 = ceil(6250/16))

typedef __attribute__((ext_vector_type(8))) short short8;   // 8 bf16 (4 VGPRs)
typedef __attribute__((ext_vector_type(4))) float floatx4;  // MFMA acc / f32x4
typedef __attribute__((ext_vector_type(4))) unsigned uintx4;

__device__ __forceinline__ unsigned short f2bf(float f) {   // RNE f32->bf16
    unsigned u = __float_as_uint(f);
    u += 0x7FFF + ((u >> 16) & 1);
    return (unsigned short)(u >> 16);
}

__device__ __forceinline__ float sigmoidf(float x) {
    return 1.f / (1.f + __expf(-x));
}

__device__ __forceinline__ void gproc4(unsigned r, const unsigned short* __restrict__ xt,
                                       int sub, floatx4& a0, floatx4& a1) {
    const unsigned src = r & 0xFFFFu;
    const float a = __uint_as_float(r & 0xFFFF0000u);
    const uint4 p = *(const uint4*)(xt + (size_t)src * D + sub * 8);
    a0[0] = fmaf(a, __uint_as_float(p.x << 16),         a0[0]);
    a0[1] = fmaf(a, __uint_as_float(p.x & 0xFFFF0000u), a0[1]);
    a0[2] = fmaf(a, __uint_as_float(p.y << 16),         a0[2]);
    a0[3] = fmaf(a, __uint_as_float(p.y & 0xFFFF0000u), a0[3]);
    a1[0] = fmaf(a, __uint_as_float(p.z << 16),         a1[0]);
    a1[1] = fmaf(a, __uint_as_float(p.z & 0xFFFF0000u), a1[1]);
    a1[2] = fmaf(a, __uint_as_float(p.w << 16),         a1[2]);
    a1[3] = fmaf(a, __uint_as_float(p.w & 0xFFFF0000u), a1[3]);
}

// ---------------------------------------------------------------------------
// ONE cooperative kernel, 4 phases separated by grid.sync(). All phases
// GRID-STRIDE (stride = gridDim.x, a multiple of 8, so unit&7 == bid&7 and
// the XCD-range mapping of scatter/gather is preserved at any grid size).
// Grid sized by the HOST from real occupancy -- R8's failure was a silent
// hipErrorCooperativeLaunchTooLarge (2048 blocks @ forced 8/CU unsatisfiable).
// ---------------------------------------------------------------------------
__global__ void mono_kernel(
        const float* __restrict__ x,
        const float* __restrict__ W,
        const float* __restrict__ rel,
        const float* __restrict__ Wattn,
        const int* __restrict__ src_idx,
        const int* __restrict__ tgt_idx,
        const int* __restrict__ etype,
        unsigned short* __restrict__ Wbf,
        unsigned short* __restrict__ xt,
        float* __restrict__ s_node,
        float* __restrict__ s_rel,
        int* __restrict__ count,
        unsigned* __restrict__ sorted,
        float* __restrict__ out) {
    __shared__ float ls_rel[N_REL];
    const int bid  = blockIdx.x;
    const int tid  = threadIdx.x;
    const int gdim = gridDim.x;
    cg::grid_group gg = cg::this_grid();

    // ---------------- Phase A0: Wbf, s_rel, count-zero ----------------
    for (int u = bid; u < A0_UNITS; u += gdim) {
        if (u < 64) {
            const int i = u * 256 + tid;              // 16384 W elements
            Wbf[i] = f2bf(W[i]);
        } else if (u < 114) {
            const int wave = (u - 64) * 4 + (tid >> 6);
            const int lane = tid & 63;
            if (wave < N_REL) {
                const float* __restrict__ row = rel + (size_t)wave * D;
                float a = fmaf(row[lane], Wattn[lane],
                               row[lane + 64] * Wattn[lane + 64]);
#pragma unroll
                for (int off = 32; off; off >>= 1)
                    a += __shfl_down(a, off);
                if (lane == 0) s_rel[wave] = a;
            }
        } else {
            const int i = (u - 114) * 256 + tid;
            if (i < N_NODES) count[i] = 0;
        }
    }
    __threadfence();
    gg.sync();

    // ---------------- Phase A1: xtrans (MFMA) + fused s_node ----------------
    for (int u = bid; u < A1_UNITS; u += gdim) {
        const int wv = u * 4 + (tid >> 6);
        if (wv < XT_WAVES2) {
            const int ng   = wv >> 1;                 // 16-node group
            const int hf   = wv & 1;                  // column half
            const int lane = tid & 63;
            const int r16  = lane & 15;
            const int quad = lane >> 4;
            const int m0   = ng * 16;

            short8 af[4];
            float  sn = 0.f;
#pragma unroll
            for (int s = 0; s < 4; ++s) {
                const int k0 = s * 32 + quad * 8;
                const float* __restrict__ xr = x + (size_t)(m0 + r16) * D + k0;
                const float4 lo = *(const float4*)(xr);
                const float4 hi = *(const float4*)(xr + 4);
                if (hf == 0) {                        // wave-uniform branch
                    const float4 wl = *(const float4*)(Wattn + k0);
                    const float4 wh = *(const float4*)(Wattn + k0 + 4);
                    sn = fmaf(lo.x, wl.x, sn); sn = fmaf(lo.y, wl.y, sn);
                    sn = fmaf(lo.z, wl.z, sn); sn = fmaf(lo.w, wl.w, sn);
                    sn = fmaf(hi.x, wh.x, sn); sn = fmaf(hi.y, wh.y, sn);
                    sn = fmaf(hi.z, wh.z, sn); sn = fmaf(hi.w, wh.w, sn);
                }
                short8 a;
                a[0] = (short)f2bf(lo.x); a[1] = (short)f2bf(lo.y);
                a[2] = (short)f2bf(lo.z); a[3] = (short)f2bf(lo.w);
                a[4] = (short)f2bf(hi.x); a[5] = (short)f2bf(hi.y);
                a[6] = (short)f2bf(hi.z); a[7] = (short)f2bf(hi.w);
                af[s] = a;
            }
            if (hf == 0) {
                sn += __shfl_xor(sn, 16);
                sn += __shfl_xor(sn, 32);
                if (lane < 16) s_node[m0 + r16] = sn;
            }

#pragma unroll
            for (int t = 0; t < 4; ++t) {
                const int tt = hf * 4 + t;
                floatx4 acc = {0.f, 0.f, 0.f, 0.f};
#pragma unroll
                for (int s = 0; s < 4; ++s) {
                    const int k0 = s * 32 + quad * 8;
                    const short8 bfrag =
                        *(const short8*)(Wbf + (size_t)(tt * 16 + r16) * D + k0);
                    acc = __builtin_amdgcn_mfma_f32_16x16x32_bf16(af[s], bfrag, acc, 0, 0, 0);
                }
#pragma unroll
                for (int r = 0; r < 4; ++r) {
                    const int orow = m0 + quad * 4 + r;
                    xt[(size_t)orow * D + tt * 16 + r16] = f2bf(acc[r]);
                }
            }
        }
    }
    __threadfence();
    gg.sync();

    // ---------------- Phase B: XCD-partitioned scatter ----------------
    if (tid < N_REL) ls_rel[tid] = s_rel[tid];
    __syncthreads();
    for (int u = bid; u < SC_UNITS; u += gdim) {     // u&7 == bid&7 == XCD
        const int lo   = (u & 7) * NODES_PER_RANGE;
        const int hi   = lo + NODES_PER_RANGE;
        const int base = (u >> 3) * CHUNK_EDGES + tid;
#pragma unroll
        for (int it = 0; it < CHUNK_EDGES / 256; ++it) {
            const int e = base + it * 256;
            const int t = tgt_idx[e];                // coalesced, cached
            const int s = src_idx[e];                // coalesced, unconditional
            const int r = etype[e];                  // coalesced, unconditional
            if (t >= lo && t < hi) {
                const float logit = s_node[s] + ls_rel[r];
                const unsigned rec =
                    ((unsigned)f2bf(sigmoidf(logit)) << 16) | (unsigned)s;
                const int k = atomicAdd(&count[t], 1);
                sorted[t * CAP + k] = rec;           // XCD-local L2 write
            }
        }
    }
    __threadfence();
    gg.sync();

    // ---------------- Phase C: gather + ReLU ----------------
    for (int u = bid; u < G_UNITS; u += gdim) {      // u&7 == bid&7 == XCD
        const int rng   = u & 7;
        const int idx   = u >> 3;                    // 0..390
        const int w     = tid >> 6;
        const int lane  = tid & 63;
        const int q     = lane >> 4;
        const int sub   = lane & 15;
        const int local = idx * 16 + w * 4 + q;
        if (local < NODES_PER_RANGE) {
            const int t = rng * NODES_PER_RANGE + local;
            const int cnt = count[t];
            const unsigned* __restrict__ rec = sorted + (size_t)t * CAP;

            floatx4 a0 = {0.f, 0.f, 0.f, 0.f};
            floatx4 a1 = {0.f, 0.f, 0.f, 0.f};
            int i = 0;
            for (; i + 4 <= cnt; i += 4) {
                const uintx4 r4 = __builtin_nontemporal_load((const uintx4*)(rec + i));
                gproc4(r4.x, xt, sub, a0, a1);
                gproc4(r4.y, xt, sub, a0, a1);
                gproc4(r4.z, xt, sub, a0, a1);
                gproc4(r4.w, xt, sub, a0, a1);
            }
            for (; i < cnt; ++i)
                gproc4(__builtin_nontemporal_load(rec + i), xt, sub, a0, a1);

            floatx4 o0, o1;
            o0[0] = fmaxf(a0[0], 0.f); o0[1] = fmaxf(a0[1], 0.f);
            o0[2] = fmaxf(a0[2], 0.f); o0[3] = fmaxf(a0[3], 0.f);
            o1[0] = fmaxf(a1[0], 0.f); o1[1] = fmaxf(a1[1], 0.f);
            o1[2] = fmaxf(a1[2], 0.f); o1[3] = fmaxf(a1[3], 0.f);
            floatx4* orow = (floatx4*)(out + (size_t)t * D) + sub * 2;
            __builtin_nontemporal_store(o0, orow);
            __builtin_nontemporal_store(o1, orow + 1);
        }
    }
}

extern "C" void kernel_launch(void* const* d_in, const int* in_sizes, int n_in,
                              void* d_out, int out_size, void* d_ws, size_t ws_size,
                              hipStream_t stream) {
    const float* x        = (const float*)d_in[0];              // [N, 128]
    const int*   edge_idx = (const int*)d_in[1];                // [2, E]
    const int*   etype    = (const int*)d_in[2];                // [E]
    const float* rel_emb  = (const float*)d_in[3];              // [R, 128]
    const float* W_lin    = (const float*)d_in[4];              // [128, 128]
    const float* W_attn   = (const float*)d_in[5];              // [1, 128]
    float* out = (float*)d_out;                                 // [N, 128]

    const int* src_idx = edge_idx;
    const int* tgt_idx = edge_idx + N_EDGES;

    // workspace layout (~26 MB total)
    unsigned short* xt   = (unsigned short*)d_ws;               // 12.8 MB (bf16)
    float* s_node        = (float*)(xt + (size_t)N_NODES * D);  // 200 KB
    float* s_rel         = s_node + N_NODES;                    // 800 B
    unsigned short* Wbf  = (unsigned short*)(s_rel + N_REL);    // 32 KB (bf16)
    int*   count         = (int*)(Wbf + D * D);                 // 200 KB
    unsigned* sorted     = (unsigned*)(count + N_NODES);        // 12.8 MB

    // Grid from REAL occupancy (host math only; cached). R8 failed because a
    // fixed 2048-block cooperative launch exceeded actual co-residency and
    // silently no-opped (hipErrorCooperativeLaunchTooLarge -> zero output).
    static int grid = 0;
    if (grid == 0) {
        int dev = 0;
        hipGetDevice(&dev);
        hipDeviceProp_t prop;
        hipGetDeviceProperties(&prop, dev);
        int maxb = 0;
        hipOccupancyMaxActiveBlocksPerMultiprocessor(&maxb, mono_kernel, 256, 0);
        if (maxb < 1) maxb = 1;
        long g = (long)maxb * prop.multiProcessorCount;
        g &= ~7L;                                    // multiple of 8 (XCD map)
        if (g > 2048) g = 2048;
        if (g < 8) g = 8;
        grid = (int)g;
    }

    void* kargs[] = {
        (void*)&x, (void*)&W_lin, (void*)&rel_emb, (void*)&W_attn,
        (void*)&src_idx, (void*)&tgt_idx, (void*)&etype,
        (void*)&Wbf, (void*)&xt, (void*)&s_node, (void*)&s_rel,
        (void*)&count, (void*)&sorted, (void*)&out
    };
    hipLaunchCooperativeKernel((void*)mono_kernel,
                               dim3(grid), dim3(256), kargs, 0, stream);
}

// Round 10
// 153.671 us; speedup vs baseline: 3.2622x; 3.2622x over previous
//
#include <hip/hip_runtime.h>
#include <hip/hip_bf16.h>

#define N_NODES 50000
#define N_EDGES 640000
#define N_REL   200
#define D       128
#define CAP     64              // bucket capacity; max degree ~35 (Poisson 12.8)
#define RANGES  8               // one target-range per XCD
#define NODES_PER_RANGE (N_NODES / RANGES)   // 6250
#define CHUNK_EDGES 2560
#define N_CHUNKS (N_EDGES / CHUNK_EDGES)     // 250

// pre_kernel block ranges (R4-exact)
#define XT_WAVES   (N_NODES / 16)            // 3125
#define XT_BLOCKS  782                       // ceil(3125/4)
#define SREL_BLOCKS 50                       // 200 waves
#define CNT_BLOCKS 196                       // 50176 threads >= N_NODES
#define PRE_BLOCKS (XT_BLOCKS + SREL_BLOCKS + CNT_BLOCKS)

// gather geometry: 4 nodes per wave, XCD-matched (blockIdx&7 == range)
#define G_BLOCKS_PER_RANGE 391               // ceil(6250/16)

typedef __attribute__((ext_vector_type(8))) short short8;   // 8 bf16 (4 VGPRs)
typedef __attribute__((ext_vector_type(4))) float floatx4;  // MFMA acc / f32x4
typedef __attribute__((ext_vector_type(4))) unsigned uintx4;

__device__ __forceinline__ unsigned short f2bf(float f) {   // RNE f32->bf16
    unsigned u = __float_as_uint(f);
    u += 0x7FFF + ((u >> 16) & 1);
    return (unsigned short)(u >> 16);
}

__device__ __forceinline__ float sigmoidf(float x) {
    return 1.f / (1.f + __expf(-x));
}

// ---------------------------------------------------------------------------
// Kernel 1 (pre, R4-exact): everything before scatter, one kernel.
//   blocks 0..781   : xtrans via MFMA. W f32->bf16 in a 32 KB XOR-swizzled
//                     LDS tile per block. Fused s_node (x read exactly once).
//   blocks 782..831 : s_rel[r] = dot(rel_emb[r], W_attn)
//   blocks 832..1027: zero count[]
// ---------------------------------------------------------------------------
__global__ __launch_bounds__(256) void pre_kernel(
        const float* __restrict__ x,
        const float* __restrict__ W,
        const float* __restrict__ rel,
        const float* __restrict__ Wattn,
        unsigned short* __restrict__ xt,
        float* __restrict__ s_node,
        float* __restrict__ s_rel,
        int* __restrict__ count) {
    __shared__ unsigned short lw[D * D];      // 32 KB swizzled bf16 W
    const int b = blockIdx.x;

    if (b < XT_BLOCKS) {
        // ---- stage W into swizzled LDS (all 256 threads) ----
        const int tid = threadIdx.x;
#pragma unroll
        for (int i = 0; i < 8; ++i) {
            const int idx8 = tid + i * 256;           // 8-element group id
            const int row  = idx8 >> 4;               // 0..127
            const int kk   = idx8 & 15;               // k0/8
            const float* __restrict__ wr = W + (size_t)row * D + kk * 8;
            const float4 lo = *(const float4*)(wr);
            const float4 hi = *(const float4*)(wr + 4);
            short8 v;
            v[0] = (short)f2bf(lo.x); v[1] = (short)f2bf(lo.y);
            v[2] = (short)f2bf(lo.z); v[3] = (short)f2bf(lo.w);
            v[4] = (short)f2bf(hi.x); v[5] = (short)f2bf(hi.y);
            v[6] = (short)f2bf(hi.z); v[7] = (short)f2bf(hi.w);
            const int slot = (row * 16 + kk) ^ (row & 7);
            *(short8*)((char*)lw + slot * 16) = v;
        }
        __syncthreads();

        const int wid = b * 4 + (threadIdx.x >> 6);
        if (wid >= XT_WAVES) return;               // last 3 waves idle
        const int lane = threadIdx.x & 63;
        const int r16  = lane & 15;
        const int quad = lane >> 4;
        const int m0   = wid * 16;

        short8 af[4];
        float  sn = 0.f;                            // dot(x[row], W_attn)
#pragma unroll
        for (int s = 0; s < 4; ++s) {
            const int k0 = s * 32 + quad * 8;
            const float* __restrict__ xr = x + (size_t)(m0 + r16) * D + k0;
            const float4 lo = *(const float4*)(xr);
            const float4 hi = *(const float4*)(xr + 4);
            const float4 wl = *(const float4*)(Wattn + k0);
            const float4 wh = *(const float4*)(Wattn + k0 + 4);
            sn = fmaf(lo.x, wl.x, sn); sn = fmaf(lo.y, wl.y, sn);
            sn = fmaf(lo.z, wl.z, sn); sn = fmaf(lo.w, wl.w, sn);
            sn = fmaf(hi.x, wh.x, sn); sn = fmaf(hi.y, wh.y, sn);
            sn = fmaf(hi.z, wh.z, sn); sn = fmaf(hi.w, wh.w, sn);
            short8 a;
            a[0] = (short)f2bf(lo.x); a[1] = (short)f2bf(lo.y);
            a[2] = (short)f2bf(lo.z); a[3] = (short)f2bf(lo.w);
            a[4] = (short)f2bf(hi.x); a[5] = (short)f2bf(hi.y);
            a[6] = (short)f2bf(hi.z); a[7] = (short)f2bf(hi.w);
            af[s] = a;
        }
        sn += __shfl_xor(sn, 16);
        sn += __shfl_xor(sn, 32);
        if (lane < 16) s_node[m0 + r16] = sn;      // 64B coalesced per wave

#pragma unroll
        for (int t = 0; t < 8; ++t) {
            floatx4 acc = {0.f, 0.f, 0.f, 0.f};
            const int row = t * 16 + r16;
#pragma unroll
            for (int s = 0; s < 4; ++s) {
                const int slot = (row * 16 + s * 4 + quad) ^ (row & 7);
                const short8 bfrag = *(const short8*)((const char*)lw + slot * 16);
                acc = __builtin_amdgcn_mfma_f32_16x16x32_bf16(af[s], bfrag, acc, 0, 0, 0);
            }
#pragma unroll
            for (int r = 0; r < 4; ++r) {
                const int orow = m0 + quad * 4 + r;
                xt[(size_t)orow * D + t * 16 + r16] = f2bf(acc[r]);
            }
        }
    } else if (b < XT_BLOCKS + SREL_BLOCKS) {
        const int wave = (b - XT_BLOCKS) * 4 + (threadIdx.x >> 6);
        const int lane = threadIdx.x & 63;
        if (wave < N_REL) {
            const float* __restrict__ row = rel + (size_t)wave * D;
            float a = fmaf(row[lane], Wattn[lane],
                           row[lane + 64] * Wattn[lane + 64]);
#pragma unroll
            for (int off = 32; off; off >>= 1)
                a += __shfl_down(a, off);
            if (lane == 0) s_rel[wave] = a;
        }
    } else {
        const int i = (b - XT_BLOCKS - SREL_BLOCKS) * 256 + threadIdx.x;
        if (i < N_NODES) count[i] = 0;
    }
}

// ---------------------------------------------------------------------------
// Kernel 2: XCD-partitioned bucket scatter (R4-exact: proven).
// ---------------------------------------------------------------------------
__global__ __launch_bounds__(256) void scatter_kernel(
        const int* __restrict__ src_idx,
        const int* __restrict__ tgt_idx,
        const int* __restrict__ etype,
        const float* __restrict__ s_node,
        const float* __restrict__ s_rel,
        int* __restrict__ count,
        unsigned* __restrict__ sorted) {
    __shared__ float ls_rel[N_REL];
    if (threadIdx.x < N_REL) ls_rel[threadIdx.x] = s_rel[threadIdx.x];
    __syncthreads();

    const int b     = blockIdx.x;
    const int lo    = (b & 7) * NODES_PER_RANGE;
    const int hi    = lo + NODES_PER_RANGE;
    const int base  = (b >> 3) * CHUNK_EDGES + threadIdx.x;

#pragma unroll
    for (int it = 0; it < CHUNK_EDGES / 256; ++it) {
        const int e = base + it * 256;
        const int t = tgt_idx[e];                    // coalesced, cached
        const int s = src_idx[e];                    // coalesced, unconditional
        const int r = etype[e];                      // coalesced, unconditional
        if (t >= lo && t < hi) {
            const float logit = s_node[s] + ls_rel[r];
            const unsigned rec =
                ((unsigned)f2bf(sigmoidf(logit)) << 16) | (unsigned)s;
            const int k = atomicAdd(&count[t], 1);
            sorted[t * CAP + k] = rec;               // XCD-local L2 write
        }
    }
}

// ---------------------------------------------------------------------------
// Kernel 3: gather + fused ReLU, chain-collapsed.
// CAP=64 guarantees rec[0..15] is always in-bounds -> the first 16 records
// are prefetched UNCONDITIONALLY (4 uintx4 loads issued concurrently with
// count[t]), collapsing the 3-level chain (count -> records -> rows) to 2.
// The 16 predicated row loads are then all independent (up to 16 xt rows in
// flight vs 4). Poison records beyond cnt are never consumed (predicated
// accumulate). Tail cnt>16 (~15% of nodes) falls back to a load loop.
// XCD-matched: blockIdx&7 == node range == the XCD whose scatter wrote
// these count/sorted lines.
// ---------------------------------------------------------------------------
__device__ __forceinline__ void gproc4(unsigned r, const unsigned short* __restrict__ xt,
                                       int sub, floatx4& a0, floatx4& a1) {
    const unsigned src = r & 0xFFFFu;
    const float a = __uint_as_float(r & 0xFFFF0000u);
    const uint4 p = *(const uint4*)(xt + (size_t)src * D + sub * 8);
    a0[0] = fmaf(a, __uint_as_float(p.x << 16),         a0[0]);
    a0[1] = fmaf(a, __uint_as_float(p.x & 0xFFFF0000u), a0[1]);
    a0[2] = fmaf(a, __uint_as_float(p.y << 16),         a0[2]);
    a0[3] = fmaf(a, __uint_as_float(p.y & 0xFFFF0000u), a0[3]);
    a1[0] = fmaf(a, __uint_as_float(p.z << 16),         a1[0]);
    a1[1] = fmaf(a, __uint_as_float(p.z & 0xFFFF0000u), a1[1]);
    a1[2] = fmaf(a, __uint_as_float(p.w << 16),         a1[2]);
    a1[3] = fmaf(a, __uint_as_float(p.w & 0xFFFF0000u), a1[3]);
}

__global__ __launch_bounds__(256) void gather_kernel(
        const int* __restrict__ count,
        const unsigned* __restrict__ sorted,
        const unsigned short* __restrict__ xt,
        float* __restrict__ out) {
    const int rng   = blockIdx.x & 7;
    const int idx   = blockIdx.x >> 3;               // 0..390
    const int w     = threadIdx.x >> 6;
    const int lane  = threadIdx.x & 63;
    const int q     = lane >> 4;
    const int sub   = lane & 15;
    const int local = idx * 16 + w * 4 + q;
    if (local >= NODES_PER_RANGE) return;
    const int t = rng * NODES_PER_RANGE + local;

    const unsigned* __restrict__ rec = sorted + (size_t)t * CAP;
    // speculative record prefetch -- always in-bounds, issued with count[t]
    const uintx4 q0 = __builtin_nontemporal_load((const uintx4*)(rec));
    const uintx4 q1 = __builtin_nontemporal_load((const uintx4*)(rec + 4));
    const uintx4 q2 = __builtin_nontemporal_load((const uintx4*)(rec + 8));
    const uintx4 q3 = __builtin_nontemporal_load((const uintx4*)(rec + 12));
    const int cnt = count[t];

    floatx4 a0 = {0.f, 0.f, 0.f, 0.f};
    floatx4 a1 = {0.f, 0.f, 0.f, 0.f};
#define GP(c, v) if (cnt > (c)) gproc4((v), xt, sub, a0, a1)
    GP(0,  q0.x); GP(1,  q0.y); GP(2,  q0.z); GP(3,  q0.w);
    GP(4,  q1.x); GP(5,  q1.y); GP(6,  q1.z); GP(7,  q1.w);
    GP(8,  q2.x); GP(9,  q2.y); GP(10, q2.z); GP(11, q2.w);
    GP(12, q3.x); GP(13, q3.y); GP(14, q3.z); GP(15, q3.w);
#undef GP
    for (int i = 16; i < cnt; i += 4) {              // rare tail (cnt>16)
        const uintx4 r4 = __builtin_nontemporal_load((const uintx4*)(rec + i));
        gproc4(r4.x, xt, sub, a0, a1);
        if (i + 1 < cnt) gproc4(r4.y, xt, sub, a0, a1);
        if (i + 2 < cnt) gproc4(r4.z, xt, sub, a0, a1);
        if (i + 3 < cnt) gproc4(r4.w, xt, sub, a0, a1);
    }

    floatx4 o0, o1;
    o0[0] = fmaxf(a0[0], 0.f); o0[1] = fmaxf(a0[1], 0.f);
    o0[2] = fmaxf(a0[2], 0.f); o0[3] = fmaxf(a0[3], 0.f);
    o1[0] = fmaxf(a1[0], 0.f); o1[1] = fmaxf(a1[1], 0.f);
    o1[2] = fmaxf(a1[2], 0.f); o1[3] = fmaxf(a1[3], 0.f);
    floatx4* orow = (floatx4*)(out + (size_t)t * D) + sub * 2;
    __builtin_nontemporal_store(o0, orow);
    __builtin_nontemporal_store(o1, orow + 1);
}

extern "C" void kernel_launch(void* const* d_in, const int* in_sizes, int n_in,
                              void* d_out, int out_size, void* d_ws, size_t ws_size,
                              hipStream_t stream) {
    const float* x        = (const float*)d_in[0];              // [N, 128]
    const int*   edge_idx = (const int*)d_in[1];                // [2, E]
    const int*   etype    = (const int*)d_in[2];                // [E]
    const float* rel_emb  = (const float*)d_in[3];              // [R, 128]
    const float* W_lin    = (const float*)d_in[4];              // [128, 128]
    const float* W_attn   = (const float*)d_in[5];              // [1, 128]
    float* out = (float*)d_out;                                 // [N, 128]

    const int* src_idx = edge_idx;
    const int* tgt_idx = edge_idx + N_EDGES;

    // workspace layout (~26 MB total)
    unsigned short* xt   = (unsigned short*)d_ws;               // 12.8 MB (bf16)
    float* s_node        = (float*)(xt + (size_t)N_NODES * D);  // 200 KB
    float* s_rel         = s_node + N_NODES;                    // 800 B
    int*   count         = (int*)(s_rel + N_REL);               // 200 KB
    unsigned* sorted     = (unsigned*)(count + N_NODES);        // 12.8 MB

    // 1. pre: xtrans(MFMA, W->LDS) + s_node + s_rel + count-zero
    pre_kernel<<<dim3(PRE_BLOCKS), dim3(256), 0, stream>>>(
        x, W_lin, rel_emb, W_attn, xt, s_node, s_rel, count);

    // 2. XCD-partitioned bucket scatter (2000 blocks = 250 chunks x 8 ranges)
    scatter_kernel<<<dim3(N_CHUNKS * RANGES), dim3(256), 0, stream>>>(
        src_idx, tgt_idx, etype, s_node, s_rel, count, sorted);

    // 3. gather + fused ReLU (4 nodes/wave, speculative 16-record prefetch)
    gather_kernel<<<dim3(G_BLOCKS_PER_RANGE * RANGES), dim3(256), 0, stream>>>(
        count, sorted, xt, out);
}

// Round 11
// 150.802 us; speedup vs baseline: 3.3243x; 1.0190x over previous
//
#include <hip/hip_runtime.h>
#include <hip/hip_bf16.h>

#define N_NODES 50000
#define N_EDGES 640000
#define N_REL   200
#define D       128
#define CAP     64              // bucket capacity; max degree ~35 (Poisson 12.8)
#define RANGES  8               // one target-range per XCD
#define NODES_PER_RANGE (N_NODES / RANGES)   // 6250
#define CHUNK_EDGES 2560
#define N_CHUNKS (N_EDGES / CHUNK_EDGES)     // 250

// pre_kernel block ranges (R4-exact)
#define XT_WAVES   (N_NODES / 16)            // 3125
#define XT_BLOCKS  782                       // ceil(3125/4)
#define SREL_BLOCKS 50                       // 200 waves
#define CNT_BLOCKS 196                       // 50176 threads >= N_NODES
#define PRE_BLOCKS (XT_BLOCKS + SREL_BLOCKS + CNT_BLOCKS)

// gather geometry: 4 nodes per wave, XCD-matched (blockIdx&7 == range)
#define G_BLOCKS_PER_RANGE 391               // ceil(6250/16)

typedef __attribute__((ext_vector_type(8))) short short8;   // 8 bf16 (4 VGPRs)
typedef __attribute__((ext_vector_type(4))) float floatx4;  // MFMA acc / f32x4
typedef __attribute__((ext_vector_type(4))) unsigned uintx4;

__device__ __forceinline__ unsigned short f2bf(float f) {   // RNE f32->bf16
    unsigned u = __float_as_uint(f);
    u += 0x7FFF + ((u >> 16) & 1);
    return (unsigned short)(u >> 16);
}

__device__ __forceinline__ float sigmoidf(float x) {
    return 1.f / (1.f + __expf(-x));
}

// ---------------------------------------------------------------------------
// Kernel 1 (pre, R10-exact): everything before scatter, one kernel.
//   blocks 0..781   : xtrans via MFMA. W f32->bf16 in a 32 KB XOR-swizzled
//                     LDS tile per block. Fused s_node (x read exactly once).
//   blocks 782..831 : s_rel[r] = dot(rel_emb[r], W_attn)
//   blocks 832..1027: zero count[]
// ---------------------------------------------------------------------------
__global__ __launch_bounds__(256) void pre_kernel(
        const float* __restrict__ x,
        const float* __restrict__ W,
        const float* __restrict__ rel,
        const float* __restrict__ Wattn,
        unsigned short* __restrict__ xt,
        float* __restrict__ s_node,
        float* __restrict__ s_rel,
        int* __restrict__ count) {
    __shared__ unsigned short lw[D * D];      // 32 KB swizzled bf16 W
    const int b = blockIdx.x;

    if (b < XT_BLOCKS) {
        // ---- stage W into swizzled LDS (all 256 threads) ----
        const int tid = threadIdx.x;
#pragma unroll
        for (int i = 0; i < 8; ++i) {
            const int idx8 = tid + i * 256;           // 8-element group id
            const int row  = idx8 >> 4;               // 0..127
            const int kk   = idx8 & 15;               // k0/8
            const float* __restrict__ wr = W + (size_t)row * D + kk * 8;
            const float4 lo = *(const float4*)(wr);
            const float4 hi = *(const float4*)(wr + 4);
            short8 v;
            v[0] = (short)f2bf(lo.x); v[1] = (short)f2bf(lo.y);
            v[2] = (short)f2bf(lo.z); v[3] = (short)f2bf(lo.w);
            v[4] = (short)f2bf(hi.x); v[5] = (short)f2bf(hi.y);
            v[6] = (short)f2bf(hi.z); v[7] = (short)f2bf(hi.w);
            const int slot = (row * 16 + kk) ^ (row & 7);
            *(short8*)((char*)lw + slot * 16) = v;
        }
        __syncthreads();

        const int wid = b * 4 + (threadIdx.x >> 6);
        if (wid >= XT_WAVES) return;               // last 3 waves idle
        const int lane = threadIdx.x & 63;
        const int r16  = lane & 15;
        const int quad = lane >> 4;
        const int m0   = wid * 16;

        short8 af[4];
        float  sn = 0.f;                            // dot(x[row], W_attn)
#pragma unroll
        for (int s = 0; s < 4; ++s) {
            const int k0 = s * 32 + quad * 8;
            const float* __restrict__ xr = x + (size_t)(m0 + r16) * D + k0;
            const float4 lo = *(const float4*)(xr);
            const float4 hi = *(const float4*)(xr + 4);
            const float4 wl = *(const float4*)(Wattn + k0);
            const float4 wh = *(const float4*)(Wattn + k0 + 4);
            sn = fmaf(lo.x, wl.x, sn); sn = fmaf(lo.y, wl.y, sn);
            sn = fmaf(lo.z, wl.z, sn); sn = fmaf(lo.w, wl.w, sn);
            sn = fmaf(hi.x, wh.x, sn); sn = fmaf(hi.y, wh.y, sn);
            sn = fmaf(hi.z, wh.z, sn); sn = fmaf(hi.w, wh.w, sn);
            short8 a;
            a[0] = (short)f2bf(lo.x); a[1] = (short)f2bf(lo.y);
            a[2] = (short)f2bf(lo.z); a[3] = (short)f2bf(lo.w);
            a[4] = (short)f2bf(hi.x); a[5] = (short)f2bf(hi.y);
            a[6] = (short)f2bf(hi.z); a[7] = (short)f2bf(hi.w);
            af[s] = a;
        }
        sn += __shfl_xor(sn, 16);
        sn += __shfl_xor(sn, 32);
        if (lane < 16) s_node[m0 + r16] = sn;      // 64B coalesced per wave

#pragma unroll
        for (int t = 0; t < 8; ++t) {
            floatx4 acc = {0.f, 0.f, 0.f, 0.f};
            const int row = t * 16 + r16;
#pragma unroll
            for (int s = 0; s < 4; ++s) {
                const int slot = (row * 16 + s * 4 + quad) ^ (row & 7);
                const short8 bfrag = *(const short8*)((const char*)lw + slot * 16);
                acc = __builtin_amdgcn_mfma_f32_16x16x32_bf16(af[s], bfrag, acc, 0, 0, 0);
            }
#pragma unroll
            for (int r = 0; r < 4; ++r) {
                const int orow = m0 + quad * 4 + r;
                xt[(size_t)orow * D + t * 16 + r16] = f2bf(acc[r]);
            }
        }
    } else if (b < XT_BLOCKS + SREL_BLOCKS) {
        const int wave = (b - XT_BLOCKS) * 4 + (threadIdx.x >> 6);
        const int lane = threadIdx.x & 63;
        if (wave < N_REL) {
            const float* __restrict__ row = rel + (size_t)wave * D;
            float a = fmaf(row[lane], Wattn[lane],
                           row[lane + 64] * Wattn[lane + 64]);
#pragma unroll
            for (int off = 32; off; off >>= 1)
                a += __shfl_down(a, off);
            if (lane == 0) s_rel[wave] = a;
        }
    } else {
        const int i = (b - XT_BLOCKS - SREL_BLOCKS) * 256 + threadIdx.x;
        if (i < N_NODES) count[i] = 0;
    }
}

// ---------------------------------------------------------------------------
// Kernel 2: XCD-partitioned bucket scatter (R10-exact: proven).
// ---------------------------------------------------------------------------
__global__ __launch_bounds__(256) void scatter_kernel(
        const int* __restrict__ src_idx,
        const int* __restrict__ tgt_idx,
        const int* __restrict__ etype,
        const float* __restrict__ s_node,
        const float* __restrict__ s_rel,
        int* __restrict__ count,
        unsigned* __restrict__ sorted) {
    __shared__ float ls_rel[N_REL];
    if (threadIdx.x < N_REL) ls_rel[threadIdx.x] = s_rel[threadIdx.x];
    __syncthreads();

    const int b     = blockIdx.x;
    const int lo    = (b & 7) * NODES_PER_RANGE;
    const int hi    = lo + NODES_PER_RANGE;
    const int base  = (b >> 3) * CHUNK_EDGES + threadIdx.x;

#pragma unroll
    for (int it = 0; it < CHUNK_EDGES / 256; ++it) {
        const int e = base + it * 256;
        const int t = tgt_idx[e];                    // coalesced, cached
        const int s = src_idx[e];                    // coalesced, unconditional
        const int r = etype[e];                      // coalesced, unconditional
        if (t >= lo && t < hi) {
            const float logit = s_node[s] + ls_rel[r];
            const unsigned rec =
                ((unsigned)f2bf(sigmoidf(logit)) << 16) | (unsigned)s;
            const int k = atomicAdd(&count[t], 1);
            sorted[t * CAP + k] = rec;               // XCD-local L2 write
        }
    }
}

// ---------------------------------------------------------------------------
// Kernel 3: gather + fused ReLU, BRANCHLESS head.
// R10's 16 predicated slots were 16 branches on a group-divergent cnt ->
// exec-mask churn fenced load hoisting; row loads issued in small batches,
// each node paying several serialized ~600cy L3 round-trips.
// Now: r = (i < cnt) ? rec[i] : 0 (one v_cndmask, no branch). Invalid slots
// load row 0 (real finite data -- poison-NaN-safe: fmaf(+0, finite, acc) is
// exact) with attn = +0.0f. All 16 row loads are unconditional & independent
// -> up to 16 rows in flight per node, 64 per wave. Tail cnt>16 (~15%) keeps
// the predicated loop. XCD-matched: blockIdx&7 == range == writing XCD.
// ---------------------------------------------------------------------------
__device__ __forceinline__ void gproc4(unsigned r, const unsigned short* __restrict__ xt,
                                       int sub, floatx4& a0, floatx4& a1) {
    const unsigned src = r & 0xFFFFu;
    const float a = __uint_as_float(r & 0xFFFF0000u);
    const uint4 p = *(const uint4*)(xt + (size_t)src * D + sub * 8);
    a0[0] = fmaf(a, __uint_as_float(p.x << 16),         a0[0]);
    a0[1] = fmaf(a, __uint_as_float(p.x & 0xFFFF0000u), a0[1]);
    a0[2] = fmaf(a, __uint_as_float(p.y << 16),         a0[2]);
    a0[3] = fmaf(a, __uint_as_float(p.y & 0xFFFF0000u), a0[3]);
    a1[0] = fmaf(a, __uint_as_float(p.z << 16),         a1[0]);
    a1[1] = fmaf(a, __uint_as_float(p.z & 0xFFFF0000u), a1[1]);
    a1[2] = fmaf(a, __uint_as_float(p.w << 16),         a1[2]);
    a1[3] = fmaf(a, __uint_as_float(p.w & 0xFFFF0000u), a1[3]);
}

__global__ __launch_bounds__(256) void gather_kernel(
        const int* __restrict__ count,
        const unsigned* __restrict__ sorted,
        const unsigned short* __restrict__ xt,
        float* __restrict__ out) {
    const int rng   = blockIdx.x & 7;
    const int idx   = blockIdx.x >> 3;               // 0..390
    const int w     = threadIdx.x >> 6;
    const int lane  = threadIdx.x & 63;
    const int q     = lane >> 4;
    const int sub   = lane & 15;
    const int local = idx * 16 + w * 4 + q;
    if (local >= NODES_PER_RANGE) return;
    const int t = rng * NODES_PER_RANGE + local;

    const int cnt = count[t];
    const unsigned* __restrict__ rec = sorted + (size_t)t * CAP;
    // speculative record prefetch -- always in-bounds (CAP=64)
    const uintx4 q0 = __builtin_nontemporal_load((const uintx4*)(rec));
    const uintx4 q1 = __builtin_nontemporal_load((const uintx4*)(rec + 4));
    const uintx4 q2 = __builtin_nontemporal_load((const uintx4*)(rec + 8));
    const uintx4 q3 = __builtin_nontemporal_load((const uintx4*)(rec + 12));

    unsigned rr[16];
    rr[0]  = q0.x; rr[1]  = q0.y; rr[2]  = q0.z; rr[3]  = q0.w;
    rr[4]  = q1.x; rr[5]  = q1.y; rr[6]  = q1.z; rr[7]  = q1.w;
    rr[8]  = q2.x; rr[9]  = q2.y; rr[10] = q2.z; rr[11] = q2.w;
    rr[12] = q3.x; rr[13] = q3.y; rr[14] = q3.z; rr[15] = q3.w;

    floatx4 a0 = {0.f, 0.f, 0.f, 0.f};
    floatx4 a1 = {0.f, 0.f, 0.f, 0.f};
#pragma unroll
    for (int i = 0; i < 16; ++i) {
        const unsigned r = (i < cnt) ? rr[i] : 0u;   // branchless slot select
        gproc4(r, xt, sub, a0, a1);
    }
    for (int i = 16; i < cnt; i += 4) {              // rare tail (cnt>16)
        const uintx4 r4 = __builtin_nontemporal_load((const uintx4*)(rec + i));
        gproc4(r4.x, xt, sub, a0, a1);
        if (i + 1 < cnt) gproc4(r4.y, xt, sub, a0, a1);
        if (i + 2 < cnt) gproc4(r4.z, xt, sub, a0, a1);
        if (i + 3 < cnt) gproc4(r4.w, xt, sub, a0, a1);
    }

    floatx4 o0, o1;
    o0[0] = fmaxf(a0[0], 0.f); o0[1] = fmaxf(a0[1], 0.f);
    o0[2] = fmaxf(a0[2], 0.f); o0[3] = fmaxf(a0[3], 0.f);
    o1[0] = fmaxf(a1[0], 0.f); o1[1] = fmaxf(a1[1], 0.f);
    o1[2] = fmaxf(a1[2], 0.f); o1[3] = fmaxf(a1[3], 0.f);
    floatx4* orow = (floatx4*)(out + (size_t)t * D) + sub * 2;
    __builtin_nontemporal_store(o0, orow);
    __builtin_nontemporal_store(o1, orow + 1);
}

extern "C" void kernel_launch(void* const* d_in, const int* in_sizes, int n_in,
                              void* d_out, int out_size, void* d_ws, size_t ws_size,
                              hipStream_t stream) {
    const float* x        = (const float*)d_in[0];              // [N, 128]
    const int*   edge_idx = (const int*)d_in[1];                // [2, E]
    const int*   etype    = (const int*)d_in[2];                // [E]
    const float* rel_emb  = (const float*)d_in[3];              // [R, 128]
    const float* W_lin    = (const float*)d_in[4];              // [128, 128]
    const float* W_attn   = (const float*)d_in[5];              // [1, 128]
    float* out = (float*)d_out;                                 // [N, 128]

    const int* src_idx = edge_idx;
    const int* tgt_idx = edge_idx + N_EDGES;

    // workspace layout (~26 MB total)
    unsigned short* xt   = (unsigned short*)d_ws;               // 12.8 MB (bf16)
    float* s_node        = (float*)(xt + (size_t)N_NODES * D);  // 200 KB
    float* s_rel         = s_node + N_NODES;                    // 800 B
    int*   count         = (int*)(s_rel + N_REL);               // 200 KB
    unsigned* sorted     = (unsigned*)(count + N_NODES);        // 12.8 MB

    // 1. pre: xtrans(MFMA, W->LDS) + s_node + s_rel + count-zero
    pre_kernel<<<dim3(PRE_BLOCKS), dim3(256), 0, stream>>>(
        x, W_lin, rel_emb, W_attn, xt, s_node, s_rel, count);

    // 2. XCD-partitioned bucket scatter (2000 blocks = 250 chunks x 8 ranges)
    scatter_kernel<<<dim3(N_CHUNKS * RANGES), dim3(256), 0, stream>>>(
        src_idx, tgt_idx, etype, s_node, s_rel, count, sorted);

    // 3. gather + fused ReLU (4 nodes/wave, branchless 16-slot head)
    gather_kernel<<<dim3(G_BLOCKS_PER_RANGE * RANGES), dim3(256), 0, stream>>>(
        count, sorted, xt, out);
}